// Round 16
// baseline (63.227 us; speedup 1.0000x reference)
//
#include <hip/hip_runtime.h>
#include <hip/hip_fp16.h>

#define TEX_H 256
#define TEX_W 256
#define FCH 16
#define NPIX (8 * 256 * 256)
#define NCELL (256 * 256)

#define SQRT2_F 1.41421356237f
// Interior weights (grid anchored at u-2 => du,dv exactly in {0,1,2};
// d=2 slots fail w>0.1, leaving the 3x3 with constant weights):
#define W_EDGE   0.24311673443f   // exp(-sqrt(2))
#define W_DIAG   0.13533528324f   // exp(-2)

typedef float vf4 __attribute__((ext_vector_type(4)));

// ws layout (bytes): halo payload fp16 (normalized error ~ulp(|f|), verified
// absmax 0.0078 < 0.032 in r15); boundary strips exact fp32.
//  halo_h [NCELL][16] __half   @ 0          (2,097,152 B)
//  halo_n [NCELL]     float    @ 2,097,152  (  262,144 B)
//  dir_c  [2048][16]  float    @ 2,359,296  (  131,072 B)
//  dir_w  [2048]      float    @ 2,490,368  (    8,192 B)
#define HALO_H_OFF 0
#define HALO_N_OFF (NCELL * 16 * 2)
#define DIR_C_OFF  (HALO_N_OFF + NCELL * 4)
#define DIR_W_OFF  (DIR_C_OFF + 2048 * 16 * 4)
#define ZERO_BYTES (DIR_W_OFF + 2048 * 4)

// ---- splat: UNCHANGED from r15 (proven 45us, the empirical scatter wall).
// 8 lanes per pixel; lane l owns channel pair (2l, 2l+1); one packed fp16
// atomic per lane (1 sector/pixel payload + 1 count sector). ----
__global__ __launch_bounds__(256) void splat_kernel(
    const float*  __restrict__ f_map,
    const float2* __restrict__ uv_map,
    const float*  __restrict__ mask,
    char* __restrict__ wsb)
{
    __half2* halo = (__half2*)(wsb + HALO_H_OFF);
    float*   hcnt = (float*)  (wsb + HALO_N_OFF);
    float*   dirc = (float*)  (wsb + DIR_C_OFF);
    float*   dirw = (float*)  (wsb + DIR_W_OFF);

    int tid = blockIdx.x * 256 + threadIdx.x;
    int pix = tid >> 3;
    int l   = tid & 7;

    if (mask[pix] == 0.0f) return;

    float2 uv = uv_map[pix];
    float u = uv.x * 256.0f;
    float v = uv.y * 256.0f;

    if (u >= 2.0f && v >= 2.0f) {
        int cell = ((int)v) * 256 + (int)u;          // uv<1 => indices <=255
        float2 fp = ((const float2*)f_map)[(size_t)pix * 8 + l]; // ch 2l,2l+1
        __half2 h = __floats2half2_rn(fp.x, fp.y);
        unsafeAtomicAdd(&halo[(size_t)cell * 8 + l], h);
        if (l == 0) unsafeAtomicAdd(&hcnt[cell], 1.0f);
    } else {
        // Exact reference path; passing slots have ui<4 (u<2) or vi<4 (v<2).
        float fa = f_map[(size_t)pix * FCH + l];
        float fb = f_map[(size_t)pix * FCH + l + 8];
        float us = fmaxf(u - 2.0f, 0.0f);
        float vs = fmaxf(v - 2.0f, 0.0f);
        #pragma unroll
        for (int kv = 0; kv < 4; ++kv) {
            float vg = vs + (float)kv;
            int vi = (int)vg;
            float dvf = fabsf(vg - v);
            #pragma unroll
            for (int ku = 0; ku < 4; ++ku) {
                float ug = us + (float)ku;
                int ui = (int)ug;
                float duf = fabsf(ug - u);
                float w = expf(-sqrtf(duf * duf + dvf * dvf) * SQRT2_F);
                if (w > 0.1f && vi < TEX_H && ui < TEX_W) {
                    int cell = (ui < 4) ? (ui * 256 + vi)        // region 0 (u<2)
                                        : ((4 + vi) * 256 + ui); // region 1 (vi<4)
                    unsafeAtomicAdd(&dirc[(size_t)cell * FCH + l],     w * fa);
                    unsafeAtomicAdd(&dirc[(size_t)cell * FCH + l + 8], w * fb);
                    if (l == 0) unsafeAtomicAdd(&dirw[cell], w);
                }
            }
        }
    }
}

// ---- finalize: grid 4096 = (tile 0..1023, bpair 0..3). Each WG stages the
// 10x10 halo in LDS, does the 3x3 const-weight conv, and writes TWO batch
// copies (store-issue parallelism 4x vs the 8-copy loop that capped r15's
// finalize at 2.4 TB/s). Halo re-read x4 is L2-resident (10 MB). ----
__global__ __launch_bounds__(256) void finalize_kernel(
    const char* __restrict__ wsb,
    float* __restrict__ out)
{
    const __half2* halo = (const __half2*)(wsb + HALO_H_OFF);
    const float*   hcnt = (const float*)  (wsb + HALO_N_OFF);
    const float*   dirc = (const float*)  (wsb + DIR_C_OFF);
    const float*   dirw = (const float*)  (wsb + DIR_W_OFF);

    __shared__ __half2 s_h[100][8];   // 10x10 cells x 16 ch (fp16) = 3200 B
    __shared__ float   s_n[100];

    int wg   = blockIdx.x;
    int tile = wg >> 2;                     // 0..1023 : 32x32 tiles of 8x8
    int bp   = wg & 3;                      // batch pair: writes 2*bp, 2*bp+1... (see below)
    int r0 = (tile >> 5) << 3;
    int c0 = (tile & 31) << 3;

    int i = threadIdx.x;
    if (i < 200) {                          // 2 threads per halo cell (16B each)
        int cellIdx = i >> 1, part = i & 1;
        int hr = cellIdx / 10, hc = cellIdx - hr * 10;
        int gr = r0 + hr - 1, gc = c0 + hc - 1;
        uint4 val = make_uint4(0, 0, 0, 0);
        bool inb = (gr >= 0) & (gr < 256) & (gc >= 0) & (gc < 256);
        if (inb)
            val = *(const uint4*)&halo[((size_t)gr * 256 + gc) * 8 + part * 4];
        *(uint4*)&s_h[cellIdx][part * 4] = val;
        if (part == 0) s_n[cellIdx] = inb ? hcnt[gr * 256 + gc] : 0.0f;
    }
    __syncthreads();

    int tx = threadIdx.x >> 2;              // texel in tile 0..63
    int c4 = threadIdx.x & 3;               // float4 chunk 0..3
    int lr = tx >> 3, lc = tx & 7;
    int gr = r0 + lr, gc = c0 + lc;

    vf4 cs = {0.f, 0.f, 0.f, 0.f};
    float wsm = 0.0f;

    #pragma unroll
    for (int a = 0; a < 3; ++a) {
        #pragma unroll
        for (int b = 0; b < 3; ++b) {
            float w = (a == 1 && b == 1) ? 1.0f
                    : ((a == 1 || b == 1) ? W_EDGE : W_DIAG);
            int idx = (lr + a) * 10 + (lc + b);
            float2 f0 = __half22float2(s_h[idx][c4 * 2 + 0]);
            float2 f1 = __half22float2(s_h[idx][c4 * 2 + 1]);
            cs.x += w * f0.x; cs.y += w * f0.y;
            cs.z += w * f1.x; cs.w += w * f1.y;
            wsm  += w * s_n[idx];
        }
    }

    // Boundary strip merge (exact fp32; region mapping matches splat).
    if (gc < 4) {
        int cell = gc * 256 + gr;
        cs += *(const vf4*)&dirc[(size_t)cell * FCH + c4 * 4];
        wsm += dirw[cell];
    } else if (gr < 4) {
        int cell = (4 + gr) * 256 + gc;
        cs += *(const vf4*)&dirc[(size_t)cell * FCH + c4 * 4];
        wsm += dirw[cell];
    }

    float s = (wsm > 0.01f) ? (1.0f / (wsm + 0.001f)) : 0.0f;
    cs *= s;

    size_t base = ((size_t)gr * 256 + gc) * FCH + c4 * 4;
    // batches bp and bp+4 (spread pairs across address space)
    __builtin_nontemporal_store(cs, (vf4*)&out[(size_t)bp       * (256 * 256 * FCH) + base]);
    __builtin_nontemporal_store(cs, (vf4*)&out[(size_t)(bp + 4) * (256 * 256 * FCH) + base]);
}

extern "C" void kernel_launch(void* const* d_in, const int* in_sizes, int n_in,
                              void* d_out, int out_size, void* d_ws, size_t ws_size,
                              hipStream_t stream) {
    const float*  f_map  = (const float*)d_in[0];
    const float2* uv_map = (const float2*)d_in[1];
    const float*  mask   = (const float*)d_in[2];
    float* out = (float*)d_out;
    char*  wsb = (char*)d_ws;

    (void)hipMemsetAsync(wsb, 0, (size_t)ZERO_BYTES, stream);

    splat_kernel<<<(NPIX * 8) / 256, 256, 0, stream>>>(f_map, uv_map, mask, wsb);
    finalize_kernel<<<4096, 256, 0, stream>>>(wsb, out);
}